// Round 1
// baseline (380.378 us; speedup 1.0000x reference)
//
#include <hip/hip_runtime.h>
#include <math.h>

// FeatureWeightNet: grid_sample(bilinear,border,align_corners=False) ->
// group correlation (G=8, C/G=8) -> 1x1 conv(8->16)+BN(batch stats)+ReLU ->
// 1x1 conv(16->8)+BN+ReLU -> 1x1 conv(8->1)+bias -> sigmoid.
// All fp32. BN batch statistics force multi-pass: sample->stats->stats->final.

constexpr int   Bc  = 2;
constexpr int   Cc  = 64;
constexpr int   Hc  = 256;
constexpr int   Wc  = 320;
constexpr int   NBc = 9;
constexpr int   HWc = Hc * Wc;            // 81920
constexpr int   NPIX = Bc * HWc;          // 163840
constexpr int   NPT  = Bc * NBc * HWc;    // 1474560 (= out_size)
constexpr float EPSV = 1e-5f;

constexpr int NB1 = 512;   // stats1 partial blocks
constexpr int NB2 = 512;   // stats2 partial blocks

// workspace layout in floats (~89 MB total)
constexpr size_t OFF_FEATT = 0;                              // NHWC feature: NPIX*64
constexpr size_t OFF_S     = OFF_FEATT + (size_t)NPIX * 64;  // s buffer: NPT*8
constexpr size_t OFF_P1    = OFF_S + (size_t)NPT * 8;        // NB1*32
constexpr size_t OFF_BN1   = OFF_P1 + (size_t)NB1 * 32;      // a1[16], c1[16]
constexpr size_t OFF_P2    = OFF_BN1 + 32;                   // NB2*16
constexpr size_t OFF_BN2   = OFF_P2 + (size_t)NB2 * 16;      // a2[8], c2[8]

// ---------------------------------------------------------------------------
// K0: NCHW -> NHWC transpose of ref_feature (64 ch).  LDS tile 64x64, +1 pad.
__global__ __launch_bounds__(256) void k_transpose(
    const float* __restrict__ feat, float* __restrict__ featT) {
  __shared__ float lds[64][65];
  const int tid  = threadIdx.x;
  const int b    = blockIdx.x / (HWc / 64);
  const int tile = blockIdx.x % (HWc / 64);
  const int hw0  = tile * 64;
  const int p    = tid & 63;
  const int ty   = tid >> 6;  // 0..3

  const float* src = feat + (size_t)b * Cc * HWc + hw0 + p;
#pragma unroll
  for (int c0 = 0; c0 < 64; c0 += 4) {
    lds[c0 + ty][p] = src[(size_t)(c0 + ty) * HWc];
  }
  __syncthreads();
  const int ch = tid & 63;
  float* dst = featT + ((size_t)b * HWc + hw0) * 64 + ch;
#pragma unroll
  for (int p0 = 0; p0 < 64; p0 += 4) {
    dst[(size_t)(p0 + ty) * 64] = lds[ch][p0 + ty];
  }
}

// ---------------------------------------------------------------------------
// K1: grid sample + group correlation.  8 lanes per pixel; lane j owns group j
// (channels j*8..j*8+7).  Loops the 9 neighbors, ref vector loaded once.
__global__ __launch_bounds__(256) void k_sample(
    const float* __restrict__ grid, const float* __restrict__ featT,
    float* __restrict__ sOut) {
  const int tid = threadIdx.x;
  const int cid = blockIdx.x * 32 + (tid >> 3);  // pixel id in [0, NPIX)
  const int j   = tid & 7;                       // group / lane-in-cluster
  const int b   = cid / HWc;
  const int hw  = cid - b * HWc;
  const int h   = hw / Wc;
  const int w   = hw - h * Wc;

  // batch base in float4 units (64 floats = 16 float4 per pixel)
  const float4* fb = (const float4*)(featT) + (size_t)b * HWc * 16;
  const float4* refp = (const float4*)(featT) + (size_t)cid * 16 + j * 2;
  const float4 r0 = refp[0];
  const float4 r1 = refp[1];

#pragma unroll 3
  for (int n = 0; n < NBc; ++n) {
    const size_t gi = ((((size_t)b * NBc + n) * Hc + h) * Wc + w) * 2;
    const float2 g2 = *(const float2*)(grid + gi);
    float ix = ((g2.x + 1.f) * (float)Wc - 1.f) * 0.5f;
    float iy = ((g2.y + 1.f) * (float)Hc - 1.f) * 0.5f;
    ix = fminf(fmaxf(ix, 0.f), (float)(Wc - 1));
    iy = fminf(fmaxf(iy, 0.f), (float)(Hc - 1));
    const float x0f = floorf(ix), y0f = floorf(iy);
    const float fx = ix - x0f, fy = iy - y0f;
    const int x0 = (int)x0f, y0 = (int)y0f;
    const int x1 = min(x0 + 1, Wc - 1), y1 = min(y0 + 1, Hc - 1);
    const float w00 = (1.f - fx) * (1.f - fy);
    const float w01 = fx * (1.f - fy);
    const float w10 = (1.f - fx) * fy;
    const float w11 = fx * fy;

    const float4* t00 = fb + (size_t)(y0 * Wc + x0) * 16 + j * 2;
    const float4* t01 = fb + (size_t)(y0 * Wc + x1) * 16 + j * 2;
    const float4* t10 = fb + (size_t)(y1 * Wc + x0) * 16 + j * 2;
    const float4* t11 = fb + (size_t)(y1 * Wc + x1) * 16 + j * 2;
    const float4 a0 = t00[0], a1 = t00[1];
    const float4 b0 = t01[0], b1 = t01[1];
    const float4 c0 = t10[0], c1 = t10[1];
    const float4 d0 = t11[0], d1 = t11[1];

    float s;
    s  = (w00 * a0.x + w01 * b0.x + w10 * c0.x + w11 * d0.x) * r0.x;
    s += (w00 * a0.y + w01 * b0.y + w10 * c0.y + w11 * d0.y) * r0.y;
    s += (w00 * a0.z + w01 * b0.z + w10 * c0.z + w11 * d0.z) * r0.z;
    s += (w00 * a0.w + w01 * b0.w + w10 * c0.w + w11 * d0.w) * r0.w;
    s += (w00 * a1.x + w01 * b1.x + w10 * c1.x + w11 * d1.x) * r1.x;
    s += (w00 * a1.y + w01 * b1.y + w10 * c1.y + w11 * d1.y) * r1.y;
    s += (w00 * a1.z + w01 * b1.z + w10 * c1.z + w11 * d1.z) * r1.z;
    s += (w00 * a1.w + w01 * b1.w + w10 * c1.w + w11 * d1.w) * r1.w;
    s *= 0.125f;  // mean over C/G = 8

    const size_t pt = ((size_t)b * NBc + n) * HWc + hw;
    sOut[pt * 8 + j] = s;
  }
}

// ---------------------------------------------------------------------------
// K2: per-block partial sums of y and y^2, y = w0 @ s (16 channels).
__global__ __launch_bounds__(256) void k_stats1(
    const float* __restrict__ sBuf, const float* __restrict__ w0,
    float* __restrict__ partials) {
  __shared__ float w0s[128];
  __shared__ float red[4 * 32];
  const int tid = threadIdx.x;
  if (tid < 128) w0s[tid] = w0[tid];
  __syncthreads();

  float sy[16], sy2[16];
#pragma unroll
  for (int c = 0; c < 16; ++c) { sy[c] = 0.f; sy2[c] = 0.f; }

  const int stride = gridDim.x * blockDim.x;
  for (int p = blockIdx.x * blockDim.x + tid; p < NPT; p += stride) {
    const float4* sp = (const float4*)(sBuf + (size_t)p * 8);
    const float4 s0 = sp[0], s1 = sp[1];
#pragma unroll
    for (int c = 0; c < 16; ++c) {
      const float* wr = w0s + c * 8;
      const float y = wr[0] * s0.x + wr[1] * s0.y + wr[2] * s0.z + wr[3] * s0.w +
                      wr[4] * s1.x + wr[5] * s1.y + wr[6] * s1.z + wr[7] * s1.w;
      sy[c] += y;
      sy2[c] += y * y;
    }
  }
#pragma unroll
  for (int c = 0; c < 16; ++c) {
    for (int off = 32; off >= 1; off >>= 1) {
      sy[c] += __shfl_xor(sy[c], off);
      sy2[c] += __shfl_xor(sy2[c], off);
    }
  }
  const int wid = tid >> 6;
  if ((tid & 63) == 0) {
#pragma unroll
    for (int c = 0; c < 16; ++c) {
      red[wid * 32 + c] = sy[c];
      red[wid * 32 + 16 + c] = sy2[c];
    }
  }
  __syncthreads();
  if (tid < 32) {
    partials[(size_t)blockIdx.x * 32 + tid] =
        red[tid] + red[32 + tid] + red[64 + tid] + red[96 + tid];
  }
}

// K3: finalize BN1 -> a1[16], c1[16]
__global__ __launch_bounds__(256) void k_fin1(
    const float* __restrict__ partials, const float* __restrict__ g0,
    const float* __restrict__ b0, float* __restrict__ bn1) {
  __shared__ float acc[256];
  __shared__ float tot[32];
  const int tid = threadIdx.x;
  const int v = tid & 31, chunk = tid >> 5;  // 8 chunks
  float sm = 0.f;
  for (int b = chunk; b < NB1; b += 8) sm += partials[(size_t)b * 32 + v];
  acc[tid] = sm;
  __syncthreads();
  if (tid < 32) {
    float t = 0.f;
#pragma unroll
    for (int k = 0; k < 8; ++k) t += acc[k * 32 + tid];
    tot[tid] = t;
  }
  __syncthreads();
  if (tid < 16) {
    const float invN = 1.f / (float)NPT;
    const float mean = tot[tid] * invN;
    const float var = tot[tid + 16] * invN - mean * mean;
    const float a = g0[tid] * rsqrtf(var + EPSV);
    bn1[tid] = a;
    bn1[16 + tid] = b0[tid] - mean * a;
  }
}

// ---------------------------------------------------------------------------
// K4: partial sums of z and z^2, z = w1 @ relu(a1*(w0@s)+c1) (8 channels).
__global__ __launch_bounds__(256) void k_stats2(
    const float* __restrict__ sBuf, const float* __restrict__ w0,
    const float* __restrict__ w1, const float* __restrict__ bn1,
    float* __restrict__ partials) {
  __shared__ float w0s[128], w1s[128], a1s[16], c1s[16];
  __shared__ float red[4 * 16];
  const int tid = threadIdx.x;
  if (tid < 128) { w0s[tid] = w0[tid]; w1s[tid] = w1[tid]; }
  if (tid < 16) { a1s[tid] = bn1[tid]; c1s[tid] = bn1[16 + tid]; }
  __syncthreads();

  float sz[8], sz2[8];
#pragma unroll
  for (int o = 0; o < 8; ++o) { sz[o] = 0.f; sz2[o] = 0.f; }

  const int stride = gridDim.x * blockDim.x;
  for (int p = blockIdx.x * blockDim.x + tid; p < NPT; p += stride) {
    const float4* sp = (const float4*)(sBuf + (size_t)p * 8);
    const float4 s0 = sp[0], s1 = sp[1];
    float x1[16];
#pragma unroll
    for (int c = 0; c < 16; ++c) {
      const float* wr = w0s + c * 8;
      const float y = wr[0] * s0.x + wr[1] * s0.y + wr[2] * s0.z + wr[3] * s0.w +
                      wr[4] * s1.x + wr[5] * s1.y + wr[6] * s1.z + wr[7] * s1.w;
      x1[c] = fmaxf(a1s[c] * y + c1s[c], 0.f);
    }
#pragma unroll
    for (int o = 0; o < 8; ++o) {
      const float* wr = w1s + o * 16;
      float z = 0.f;
#pragma unroll
      for (int k = 0; k < 16; ++k) z += wr[k] * x1[k];
      sz[o] += z;
      sz2[o] += z * z;
    }
  }
#pragma unroll
  for (int o = 0; o < 8; ++o) {
    for (int off = 32; off >= 1; off >>= 1) {
      sz[o] += __shfl_xor(sz[o], off);
      sz2[o] += __shfl_xor(sz2[o], off);
    }
  }
  const int wid = tid >> 6;
  if ((tid & 63) == 0) {
#pragma unroll
    for (int o = 0; o < 8; ++o) {
      red[wid * 16 + o] = sz[o];
      red[wid * 16 + 8 + o] = sz2[o];
    }
  }
  __syncthreads();
  if (tid < 16) {
    partials[(size_t)blockIdx.x * 16 + tid] =
        red[tid] + red[16 + tid] + red[32 + tid] + red[48 + tid];
  }
}

// K5: finalize BN2 -> a2[8], c2[8]
__global__ __launch_bounds__(256) void k_fin2(
    const float* __restrict__ partials, const float* __restrict__ g1,
    const float* __restrict__ b1, float* __restrict__ bn2) {
  __shared__ float acc[256];
  __shared__ float tot[16];
  const int tid = threadIdx.x;
  const int v = tid & 15, chunk = tid >> 4;  // 16 chunks
  float sm = 0.f;
  for (int b = chunk; b < NB2; b += 16) sm += partials[(size_t)b * 16 + v];
  acc[tid] = sm;
  __syncthreads();
  if (tid < 16) {
    float t = 0.f;
#pragma unroll
    for (int k = 0; k < 16; ++k) t += acc[k * 16 + tid];
    tot[tid] = t;
  }
  __syncthreads();
  if (tid < 8) {
    const float invN = 1.f / (float)NPT;
    const float mean = tot[tid] * invN;
    const float var = tot[tid + 8] * invN - mean * mean;
    const float a = g1[tid] * rsqrtf(var + EPSV);
    bn2[tid] = a;
    bn2[8 + tid] = b1[tid] - mean * a;
  }
}

// ---------------------------------------------------------------------------
// K6: full epilogue: s -> MLP -> sigmoid -> out
__global__ __launch_bounds__(256) void k_final(
    const float* __restrict__ sBuf, const float* __restrict__ w0,
    const float* __restrict__ w1, const float* __restrict__ bn1,
    const float* __restrict__ bn2, const float* __restrict__ wsW,
    const float* __restrict__ bs, float* __restrict__ out) {
  __shared__ float w0s[128], w1s[128], a1s[16], c1s[16], a2s[8], c2s[8], wss[8];
  __shared__ float bss;
  const int tid = threadIdx.x;
  if (tid < 128) { w0s[tid] = w0[tid]; w1s[tid] = w1[tid]; }
  if (tid < 16) { a1s[tid] = bn1[tid]; c1s[tid] = bn1[16 + tid]; }
  if (tid < 8) { a2s[tid] = bn2[tid]; c2s[tid] = bn2[8 + tid]; wss[tid] = wsW[tid]; }
  if (tid == 0) bss = bs[0];
  __syncthreads();

  const int p = blockIdx.x * blockDim.x + tid;
  if (p >= NPT) return;
  const float4* sp = (const float4*)(sBuf + (size_t)p * 8);
  const float4 s0 = sp[0], s1 = sp[1];
  float x1[16];
#pragma unroll
  for (int c = 0; c < 16; ++c) {
    const float* wr = w0s + c * 8;
    const float y = wr[0] * s0.x + wr[1] * s0.y + wr[2] * s0.z + wr[3] * s0.w +
                    wr[4] * s1.x + wr[5] * s1.y + wr[6] * s1.z + wr[7] * s1.w;
    x1[c] = fmaxf(a1s[c] * y + c1s[c], 0.f);
  }
  float o = bss;
#pragma unroll
  for (int oc = 0; oc < 8; ++oc) {
    const float* wr = w1s + oc * 16;
    float z = 0.f;
#pragma unroll
    for (int k = 0; k < 16; ++k) z += wr[k] * x1[k];
    const float x2 = fmaxf(a2s[oc] * z + c2s[oc], 0.f);
    o += wss[oc] * x2;
  }
  out[p] = 1.f / (1.f + expf(-o));
}

// ---------------------------------------------------------------------------
extern "C" void kernel_launch(void* const* d_in, const int* in_sizes, int n_in,
                              void* d_out, int out_size, void* d_ws,
                              size_t ws_size, hipStream_t stream) {
  const float* feat = (const float*)d_in[0];  // [2,64,256,320]
  const float* grid = (const float*)d_in[1];  // [2,2304,320,2]
  const float* w0 = (const float*)d_in[2];    // [16,8]
  const float* g0 = (const float*)d_in[3];
  const float* b0 = (const float*)d_in[4];
  const float* w1 = (const float*)d_in[5];    // [8,16]
  const float* g1 = (const float*)d_in[6];
  const float* b1 = (const float*)d_in[7];
  const float* wsW = (const float*)d_in[8];   // [1,8]
  const float* bs = (const float*)d_in[9];    // [1]
  float* out = (float*)d_out;

  float* wsf = (float*)d_ws;  // requires ~90 MB of workspace
  float* featT = wsf + OFF_FEATT;
  float* sBuf  = wsf + OFF_S;
  float* p1    = wsf + OFF_P1;
  float* bn1   = wsf + OFF_BN1;
  float* p2    = wsf + OFF_P2;
  float* bn2   = wsf + OFF_BN2;

  k_transpose<<<Bc * (HWc / 64), 256, 0, stream>>>(feat, featT);
  k_sample<<<NPIX / 32, 256, 0, stream>>>(grid, featT, sBuf);
  k_stats1<<<NB1, 256, 0, stream>>>(sBuf, w0, p1);
  k_fin1<<<1, 256, 0, stream>>>(p1, g0, b0, bn1);
  k_stats2<<<NB2, 256, 0, stream>>>(sBuf, w0, w1, bn1, p2);
  k_fin2<<<1, 256, 0, stream>>>(p2, g1, b1, bn2);
  k_final<<<NPT / 256, 256, 0, stream>>>(sBuf, w0, w1, bn1, bn2, wsW, bs, out);
}

// Round 2
// 283.229 us; speedup vs baseline: 1.3430x; 1.3430x over previous
//
#include <hip/hip_runtime.h>
#include <math.h>

// FeatureWeightNet: grid_sample(bilinear,border,align_corners=False) ->
// group correlation (G=8, C/G=8) -> 1x1 conv(8->16)+BN(batch stats)+ReLU ->
// 1x1 conv(16->8)+BN+ReLU -> 1x1 conv(8->1)+bias -> sigmoid.
// R2: gather table stored as NHWC bf16 (halves TCC-miss bytes, doubles L2 hit
// rate); ref vector read exact fp32 from the original NCHW tensor.

constexpr int   Bc  = 2;
constexpr int   Cc  = 64;
constexpr int   Hc  = 256;
constexpr int   Wc  = 320;
constexpr int   NBc = 9;
constexpr int   HWc = Hc * Wc;            // 81920
constexpr int   NPIX = Bc * HWc;          // 163840
constexpr int   NPT  = Bc * NBc * HWc;    // 1474560 (= out_size)
constexpr float EPSV = 1e-5f;

constexpr int NB1 = 512;   // stats1 partial blocks
constexpr int NB2 = 512;   // stats2 partial blocks

// workspace layout in float units (~68 MB total)
constexpr size_t OFF_FEATB = 0;                              // NHWC bf16: NPIX*64 ushort = NPIX*32 floats
constexpr size_t OFF_S     = OFF_FEATB + (size_t)NPIX * 32;  // s buffer: NPT*8 floats
constexpr size_t OFF_P1    = OFF_S + (size_t)NPT * 8;        // NB1*32
constexpr size_t OFF_BN1   = OFF_P1 + (size_t)NB1 * 32;      // a1[16], c1[16]
constexpr size_t OFF_P2    = OFF_BN1 + 32;                   // NB2*16
constexpr size_t OFF_BN2   = OFF_P2 + (size_t)NB2 * 16;      // a2[8], c2[8]

__device__ __forceinline__ unsigned short f2bf_rne(float v) {
  unsigned int u = __float_as_uint(v);
  unsigned int r = (u + 0x7fffu + ((u >> 16) & 1u)) >> 16;
  return (unsigned short)r;
}

// ---------------------------------------------------------------------------
// K0: NCHW fp32 -> NHWC bf16 transpose of ref_feature (64 ch).
__global__ __launch_bounds__(256) void k_transpose(
    const float* __restrict__ feat, unsigned short* __restrict__ featB) {
  __shared__ float lds[64][65];
  const int tid  = threadIdx.x;
  const int b    = blockIdx.x / (HWc / 64);
  const int tile = blockIdx.x % (HWc / 64);
  const int hw0  = tile * 64;
  const int p    = tid & 63;
  const int ty   = tid >> 6;  // 0..3

  const float* src = feat + (size_t)b * Cc * HWc + hw0 + p;
#pragma unroll
  for (int c0 = 0; c0 < 64; c0 += 4) {
    lds[c0 + ty][p] = src[(size_t)(c0 + ty) * HWc];
  }
  __syncthreads();
  const int ch = tid & 63;
  unsigned short* dst = featB + ((size_t)b * HWc + hw0) * 64 + ch;
#pragma unroll
  for (int p0 = 0; p0 < 64; p0 += 4) {
    dst[(size_t)(p0 + ty) * 64] = f2bf_rne(lds[ch][p0 + ty]);
  }
}

// ---------------------------------------------------------------------------
__device__ __forceinline__ void unpack8(uint4 u, float f[8]) {
  f[0] = __uint_as_float(u.x << 16);
  f[1] = __uint_as_float(u.x & 0xffff0000u);
  f[2] = __uint_as_float(u.y << 16);
  f[3] = __uint_as_float(u.y & 0xffff0000u);
  f[4] = __uint_as_float(u.z << 16);
  f[5] = __uint_as_float(u.z & 0xffff0000u);
  f[6] = __uint_as_float(u.w << 16);
  f[7] = __uint_as_float(u.w & 0xffff0000u);
}

// K1: grid sample + group correlation.  8 lanes per pixel; lane j owns group j
// (channels j*8..j*8+7 = 16 B = one uint4 of bf16 per tap).
__global__ __launch_bounds__(256) void k_sample(
    const float* __restrict__ grid, const unsigned short* __restrict__ featB,
    const float* __restrict__ feat, float* __restrict__ sOut) {
  const int tid = threadIdx.x;
  const int cid = blockIdx.x * 32 + (tid >> 3);  // pixel id in [0, NPIX)
  const int j   = tid & 7;                       // group / lane-in-cluster
  const int b   = cid / HWc;
  const int hw  = cid - b * HWc;
  const int h   = hw / Wc;
  const int w   = hw - h * Wc;

  // ref vector, exact fp32 from NCHW: channels j*8..j*8+7 at (b,hw)
  const float* rp = feat + ((size_t)b * Cc + j * 8) * HWc + hw;
  float r[8];
#pragma unroll
  for (int k = 0; k < 8; ++k) r[k] = rp[(size_t)k * HWc];

  // batch base in uint4 units (64 bf16 = 8 uint4 per pixel)
  const uint4* fb = (const uint4*)featB + (size_t)b * HWc * 8;

#pragma unroll 3
  for (int n = 0; n < NBc; ++n) {
    const size_t gi = ((((size_t)b * NBc + n) * Hc + h) * Wc + w) * 2;
    const float2 g2 = *(const float2*)(grid + gi);
    float ix = ((g2.x + 1.f) * (float)Wc - 1.f) * 0.5f;
    float iy = ((g2.y + 1.f) * (float)Hc - 1.f) * 0.5f;
    ix = fminf(fmaxf(ix, 0.f), (float)(Wc - 1));
    iy = fminf(fmaxf(iy, 0.f), (float)(Hc - 1));
    const float x0f = floorf(ix), y0f = floorf(iy);
    const float fx = ix - x0f, fy = iy - y0f;
    const int x0 = (int)x0f, y0 = (int)y0f;
    const int x1 = min(x0 + 1, Wc - 1), y1 = min(y0 + 1, Hc - 1);
    const float w00 = (1.f - fx) * (1.f - fy);
    const float w01 = fx * (1.f - fy);
    const float w10 = (1.f - fx) * fy;
    const float w11 = fx * fy;

    const uint4 u00 = fb[(size_t)(y0 * Wc + x0) * 8 + j];
    const uint4 u01 = fb[(size_t)(y0 * Wc + x1) * 8 + j];
    const uint4 u10 = fb[(size_t)(y1 * Wc + x0) * 8 + j];
    const uint4 u11 = fb[(size_t)(y1 * Wc + x1) * 8 + j];
    float a[8], c[8], d[8], e[8];
    unpack8(u00, a);
    unpack8(u01, c);
    unpack8(u10, d);
    unpack8(u11, e);

    float s = 0.f;
#pragma unroll
    for (int k = 0; k < 8; ++k) {
      s += (w00 * a[k] + w01 * c[k] + w10 * d[k] + w11 * e[k]) * r[k];
    }
    s *= 0.125f;  // mean over C/G = 8

    const size_t pt = ((size_t)b * NBc + n) * HWc + hw;
    sOut[pt * 8 + j] = s;
  }
}

// ---------------------------------------------------------------------------
// K2: per-block partial sums of y and y^2, y = w0 @ s (16 channels).
__global__ __launch_bounds__(256) void k_stats1(
    const float* __restrict__ sBuf, const float* __restrict__ w0,
    float* __restrict__ partials) {
  __shared__ float w0s[128];
  __shared__ float red[4 * 32];
  const int tid = threadIdx.x;
  if (tid < 128) w0s[tid] = w0[tid];
  __syncthreads();

  float sy[16], sy2[16];
#pragma unroll
  for (int c = 0; c < 16; ++c) { sy[c] = 0.f; sy2[c] = 0.f; }

  const int stride = gridDim.x * blockDim.x;
  for (int p = blockIdx.x * blockDim.x + tid; p < NPT; p += stride) {
    const float4* sp = (const float4*)(sBuf + (size_t)p * 8);
    const float4 s0 = sp[0], s1 = sp[1];
#pragma unroll
    for (int c = 0; c < 16; ++c) {
      const float* wr = w0s + c * 8;
      const float y = wr[0] * s0.x + wr[1] * s0.y + wr[2] * s0.z + wr[3] * s0.w +
                      wr[4] * s1.x + wr[5] * s1.y + wr[6] * s1.z + wr[7] * s1.w;
      sy[c] += y;
      sy2[c] += y * y;
    }
  }
#pragma unroll
  for (int c = 0; c < 16; ++c) {
    for (int off = 32; off >= 1; off >>= 1) {
      sy[c] += __shfl_xor(sy[c], off);
      sy2[c] += __shfl_xor(sy2[c], off);
    }
  }
  const int wid = tid >> 6;
  if ((tid & 63) == 0) {
#pragma unroll
    for (int c = 0; c < 16; ++c) {
      red[wid * 32 + c] = sy[c];
      red[wid * 32 + 16 + c] = sy2[c];
    }
  }
  __syncthreads();
  if (tid < 32) {
    partials[(size_t)blockIdx.x * 32 + tid] =
        red[tid] + red[32 + tid] + red[64 + tid] + red[96 + tid];
  }
}

// K3: finalize BN1 -> a1[16], c1[16]
__global__ __launch_bounds__(256) void k_fin1(
    const float* __restrict__ partials, const float* __restrict__ g0,
    const float* __restrict__ b0, float* __restrict__ bn1) {
  __shared__ float acc[256];
  __shared__ float tot[32];
  const int tid = threadIdx.x;
  const int v = tid & 31, chunk = tid >> 5;  // 8 chunks
  float sm = 0.f;
  for (int b = chunk; b < NB1; b += 8) sm += partials[(size_t)b * 32 + v];
  acc[tid] = sm;
  __syncthreads();
  if (tid < 32) {
    float t = 0.f;
#pragma unroll
    for (int k = 0; k < 8; ++k) t += acc[k * 32 + tid];
    tot[tid] = t;
  }
  __syncthreads();
  if (tid < 16) {
    const float invN = 1.f / (float)NPT;
    const float mean = tot[tid] * invN;
    const float var = tot[tid + 16] * invN - mean * mean;
    const float a = g0[tid] * rsqrtf(var + EPSV);
    bn1[tid] = a;
    bn1[16 + tid] = b0[tid] - mean * a;
  }
}

// ---------------------------------------------------------------------------
// K4: partial sums of z and z^2, z = w1 @ relu(a1*(w0@s)+c1) (8 channels).
__global__ __launch_bounds__(256) void k_stats2(
    const float* __restrict__ sBuf, const float* __restrict__ w0,
    const float* __restrict__ w1, const float* __restrict__ bn1,
    float* __restrict__ partials) {
  __shared__ float w0s[128], w1s[128], a1s[16], c1s[16];
  __shared__ float red[4 * 16];
  const int tid = threadIdx.x;
  if (tid < 128) { w0s[tid] = w0[tid]; w1s[tid] = w1[tid]; }
  if (tid < 16) { a1s[tid] = bn1[tid]; c1s[tid] = bn1[16 + tid]; }
  __syncthreads();

  float sz[8], sz2[8];
#pragma unroll
  for (int o = 0; o < 8; ++o) { sz[o] = 0.f; sz2[o] = 0.f; }

  const int stride = gridDim.x * blockDim.x;
  for (int p = blockIdx.x * blockDim.x + tid; p < NPT; p += stride) {
    const float4* sp = (const float4*)(sBuf + (size_t)p * 8);
    const float4 s0 = sp[0], s1 = sp[1];
    float x1[16];
#pragma unroll
    for (int c = 0; c < 16; ++c) {
      const float* wr = w0s + c * 8;
      const float y = wr[0] * s0.x + wr[1] * s0.y + wr[2] * s0.z + wr[3] * s0.w +
                      wr[4] * s1.x + wr[5] * s1.y + wr[6] * s1.z + wr[7] * s1.w;
      x1[c] = fmaxf(a1s[c] * y + c1s[c], 0.f);
    }
#pragma unroll
    for (int o = 0; o < 8; ++o) {
      const float* wr = w1s + o * 16;
      float z = 0.f;
#pragma unroll
      for (int k = 0; k < 16; ++k) z += wr[k] * x1[k];
      sz[o] += z;
      sz2[o] += z * z;
    }
  }
#pragma unroll
  for (int o = 0; o < 8; ++o) {
    for (int off = 32; off >= 1; off >>= 1) {
      sz[o] += __shfl_xor(sz[o], off);
      sz2[o] += __shfl_xor(sz2[o], off);
    }
  }
  const int wid = tid >> 6;
  if ((tid & 63) == 0) {
#pragma unroll
    for (int o = 0; o < 8; ++o) {
      red[wid * 16 + o] = sz[o];
      red[wid * 16 + 8 + o] = sz2[o];
    }
  }
  __syncthreads();
  if (tid < 16) {
    partials[(size_t)blockIdx.x * 16 + tid] =
        red[tid] + red[16 + tid] + red[32 + tid] + red[48 + tid];
  }
}

// K5: finalize BN2 -> a2[8], c2[8]
__global__ __launch_bounds__(256) void k_fin2(
    const float* __restrict__ partials, const float* __restrict__ g1,
    const float* __restrict__ b1, float* __restrict__ bn2) {
  __shared__ float acc[256];
  __shared__ float tot[16];
  const int tid = threadIdx.x;
  const int v = tid & 15, chunk = tid >> 4;  // 16 chunks
  float sm = 0.f;
  for (int b = chunk; b < NB2; b += 16) sm += partials[(size_t)b * 16 + v];
  acc[tid] = sm;
  __syncthreads();
  if (tid < 16) {
    float t = 0.f;
#pragma unroll
    for (int k = 0; k < 16; ++k) t += acc[k * 16 + tid];
    tot[tid] = t;
  }
  __syncthreads();
  if (tid < 8) {
    const float invN = 1.f / (float)NPT;
    const float mean = tot[tid] * invN;
    const float var = tot[tid + 8] * invN - mean * mean;
    const float a = g1[tid] * rsqrtf(var + EPSV);
    bn2[tid] = a;
    bn2[8 + tid] = b1[tid] - mean * a;
  }
}

// ---------------------------------------------------------------------------
// K6: full epilogue: s -> MLP -> sigmoid -> out
__global__ __launch_bounds__(256) void k_final(
    const float* __restrict__ sBuf, const float* __restrict__ w0,
    const float* __restrict__ w1, const float* __restrict__ bn1,
    const float* __restrict__ bn2, const float* __restrict__ wsW,
    const float* __restrict__ bs, float* __restrict__ out) {
  __shared__ float w0s[128], w1s[128], a1s[16], c1s[16], a2s[8], c2s[8], wss[8];
  __shared__ float bss;
  const int tid = threadIdx.x;
  if (tid < 128) { w0s[tid] = w0[tid]; w1s[tid] = w1[tid]; }
  if (tid < 16) { a1s[tid] = bn1[tid]; c1s[tid] = bn1[16 + tid]; }
  if (tid < 8) { a2s[tid] = bn2[tid]; c2s[tid] = bn2[8 + tid]; wss[tid] = wsW[tid]; }
  if (tid == 0) bss = bs[0];
  __syncthreads();

  const int p = blockIdx.x * blockDim.x + tid;
  if (p >= NPT) return;
  const float4* sp = (const float4*)(sBuf + (size_t)p * 8);
  const float4 s0 = sp[0], s1 = sp[1];
  float x1[16];
#pragma unroll
  for (int c = 0; c < 16; ++c) {
    const float* wr = w0s + c * 8;
    const float y = wr[0] * s0.x + wr[1] * s0.y + wr[2] * s0.z + wr[3] * s0.w +
                    wr[4] * s1.x + wr[5] * s1.y + wr[6] * s1.z + wr[7] * s1.w;
    x1[c] = fmaxf(a1s[c] * y + c1s[c], 0.f);
  }
  float o = bss;
#pragma unroll
  for (int oc = 0; oc < 8; ++oc) {
    const float* wr = w1s + oc * 16;
    float z = 0.f;
#pragma unroll
    for (int k = 0; k < 16; ++k) z += wr[k] * x1[k];
    const float x2 = fmaxf(a2s[oc] * z + c2s[oc], 0.f);
    o += wss[oc] * x2;
  }
  out[p] = 1.f / (1.f + expf(-o));
}

// ---------------------------------------------------------------------------
extern "C" void kernel_launch(void* const* d_in, const int* in_sizes, int n_in,
                              void* d_out, int out_size, void* d_ws,
                              size_t ws_size, hipStream_t stream) {
  const float* feat = (const float*)d_in[0];  // [2,64,256,320]
  const float* grid = (const float*)d_in[1];  // [2,2304,320,2]
  const float* w0 = (const float*)d_in[2];    // [16,8]
  const float* g0 = (const float*)d_in[3];
  const float* b0 = (const float*)d_in[4];
  const float* w1 = (const float*)d_in[5];    // [8,16]
  const float* g1 = (const float*)d_in[6];
  const float* b1 = (const float*)d_in[7];
  const float* wsW = (const float*)d_in[8];   // [1,8]
  const float* bs = (const float*)d_in[9];    // [1]
  float* out = (float*)d_out;

  float* wsf = (float*)d_ws;  // requires ~68 MB of workspace
  unsigned short* featB = (unsigned short*)(wsf + OFF_FEATB);
  float* sBuf  = wsf + OFF_S;
  float* p1    = wsf + OFF_P1;
  float* bn1   = wsf + OFF_BN1;
  float* p2    = wsf + OFF_P2;
  float* bn2   = wsf + OFF_BN2;

  k_transpose<<<Bc * (HWc / 64), 256, 0, stream>>>(feat, featB);
  k_sample<<<NPIX / 32, 256, 0, stream>>>(grid, featB, feat, sBuf);
  k_stats1<<<NB1, 256, 0, stream>>>(sBuf, w0, p1);
  k_fin1<<<1, 256, 0, stream>>>(p1, g0, b0, bn1);
  k_stats2<<<NB2, 256, 0, stream>>>(sBuf, w0, w1, bn1, p2);
  k_fin2<<<1, 256, 0, stream>>>(p2, g1, b1, bn2);
  k_final<<<NPT / 256, 256, 0, stream>>>(sBuf, w0, w1, bn1, bn2, wsW, bs, out);
}